// Round 1
// baseline (318.995 us; speedup 1.0000x reference)
//
#include <hip/hip_runtime.h>

// pyGAMNet: 48 per-feature MLPs (1->40->20->1, ReLU) + 16 categorical lookups.
// Round 1: pure-VALU, LDS row-tile staging, uniform (scalar) weight loads.

#define BLOCK 128
#define ROWS 128
#define PAD 68          // floats per LDS row: 64 cols + 4 pad (keeps 16B align, breaks stride-64 conflicts)

constexpr int NB    = 131072;
constexpr int NCOLS = 64;
constexpr int NNUM  = 48;
constexpr int NCAT  = 16;
constexpr int NCLS  = 32;
constexpr int H0N   = 40;
constexpr int H1N   = 20;

__global__ __launch_bounds__(BLOCK, 2)
void gam_kernel(const float* __restrict__ inp,
                const float* __restrict__ W0, const float* __restrict__ b0,
                const float* __restrict__ W1, const float* __restrict__ b1,
                const float* __restrict__ W2, const float* __restrict__ b2,
                const float* __restrict__ cbias,
                float* __restrict__ out)
{
    __shared__ float tile[ROWS * PAD];
    __shared__ float cb[NCAT * NCLS];

    const int t = threadIdx.x;
    const long long base = (long long)blockIdx.x * (ROWS * NCOLS);

    // stage class_bias (2 KB)
    for (int i = t; i < NCAT * NCLS; i += BLOCK) cb[i] = cbias[i];

    // coalesced load of the 128x64 row tile (float4)
    {
        const float4* gin = reinterpret_cast<const float4*>(inp + base);
        #pragma unroll
        for (int j = 0; j < (ROWS * NCOLS / 4) / BLOCK; ++j) {
            int u   = j * BLOCK + t;   // float4 index within tile
            int row = u >> 4;          // 16 float4 per row
            int c4  = u & 15;
            float4 v = gin[u];
            float* dst = &tile[row * PAD + c4 * 4];
            dst[0] = v.x; dst[1] = v.y; dst[2] = v.z; dst[3] = v.w;
        }
    }
    __syncthreads();

    // compute: thread t owns local row t; results overwrite the tile in place
    float* myrow = &tile[t * PAD];

    for (int f = 0; f < NNUM; ++f) {              // f-loop kept rolled (code size)
        const float x = myrow[f];
        const float* __restrict__ w0  = W0 + f * H0N;
        const float* __restrict__ bb0 = b0 + f * H0N;
        const float* __restrict__ w1  = W1 + f * H0N * H1N;
        const float* __restrict__ bb1 = b1 + f * H1N;
        const float* __restrict__ w2  = W2 + f * H1N;

        float h0[H0N];
        #pragma unroll
        for (int k = 0; k < H0N; ++k)
            h0[k] = fmaxf(fmaf(x, w0[k], bb0[k]), 0.0f);

        float h1[H1N];
        #pragma unroll
        for (int o = 0; o < H1N; ++o) h1[o] = bb1[o];

        #pragma unroll
        for (int k = 0; k < H0N; ++k) {           // 800 v_fmac_f32, weights in SGPRs
            const float hk = h0[k];
            const float* __restrict__ w1k = w1 + k * H1N;
            #pragma unroll
            for (int o = 0; o < H1N; ++o)
                h1[o] = fmaf(hk, w1k[o], h1[o]);
        }

        float acc = b2[f];
        #pragma unroll
        for (int o = 0; o < H1N; ++o)
            acc = fmaf(fmaxf(h1[o], 0.0f), w2[o], acc);

        myrow[f] = acc;
    }

    // categorical lookups
    #pragma unroll
    for (int j = 0; j < NCAT; ++j) {
        int idx = (int)myrow[NNUM + j];
        myrow[NNUM + j] = cb[j * NCLS + idx];
    }

    __syncthreads();

    // coalesced store (mirror of the load)
    {
        float4* gout = reinterpret_cast<float4*>(out + base);
        #pragma unroll
        for (int j = 0; j < (ROWS * NCOLS / 4) / BLOCK; ++j) {
            int u   = j * BLOCK + t;
            int row = u >> 4;
            int c4  = u & 15;
            const float* src = &tile[row * PAD + c4 * 4];
            gout[u] = make_float4(src[0], src[1], src[2], src[3]);
        }
    }
}

extern "C" void kernel_launch(void* const* d_in, const int* in_sizes, int n_in,
                              void* d_out, int out_size, void* d_ws, size_t ws_size,
                              hipStream_t stream) {
    const float* inp   = (const float*)d_in[0];
    const float* W0    = (const float*)d_in[1];
    const float* b0    = (const float*)d_in[2];
    const float* W1    = (const float*)d_in[3];
    const float* b1    = (const float*)d_in[4];
    const float* W2    = (const float*)d_in[5];
    const float* b2    = (const float*)d_in[6];
    const float* cbias = (const float*)d_in[7];
    float* out = (float*)d_out;

    dim3 grid(NB / ROWS);   // 1024 blocks
    dim3 block(BLOCK);      // 128 threads
    gam_kernel<<<grid, block, 0, stream>>>(inp, W0, b0, W1, b1, W2, b2, cbias, out);
}

// Round 4
// 249.543 us; speedup vs baseline: 1.2783x; 1.2783x over previous
//
#include <hip/hip_runtime.h>

// pyGAMNet round 2 kernel (3rd submit; R2/R3 benches were broker timeouts).
// Wave-per-feature-quad, lane-per-row. Weights via s_load (wave-uniform f).

constexpr int NCOLS = 64;
constexpr int NNUM  = 48;
constexpr int NCAT  = 16;
constexpr int NCLS  = 32;
constexpr int H0N   = 40;
constexpr int H1N   = 20;

#define BLOCK 256   // 4 waves
#define RG    64    // rows per block (= lanes per wave)
#define TPAD  20    // padded cols in LDS output tile (16 used)

__global__ __launch_bounds__(BLOCK, 6)
void gam_kernel(const float* __restrict__ inp,
                const float* __restrict__ W0, const float* __restrict__ b0,
                const float* __restrict__ W1, const float* __restrict__ b1,
                const float* __restrict__ W2, const float* __restrict__ b2,
                const float* __restrict__ cbias,
                float* __restrict__ out)
{
    __shared__ float tile[RG * TPAD];   // 64 rows x 16 results (padded)
    __shared__ float cb[NCAT * NCLS];   // cat lookup table (y==3 blocks only)

    const int lane = threadIdx.x & 63;
    const int wv   = __builtin_amdgcn_readfirstlane(threadIdx.x >> 6); // wave id 0..3, SGPR
    const int fg   = blockIdx.y;                                       // feature group 0..3
    const long long row = (long long)blockIdx.x * RG + lane;
    const float* __restrict__ rowp = inp + row * NCOLS;

    if (fg == 3) {
        // stage categorical table (2 KB)
        for (int i = threadIdx.x; i < NCAT * NCLS; i += BLOCK) cb[i] = cbias[i];
    }
    __syncthreads();

    if (fg < 3) {
        // ---- numeric: this wave owns features fbase..fbase+3 ----
        const int fbase = fg * 16 + wv * 4;   // SGPR
        #pragma unroll 1
        for (int ff = 0; ff < 4; ++ff) {
            const int f = fbase + ff;                       // SGPR -> scalar weight loads
            const float x = rowp[f];                        // per-lane, L1-resident line
            const float* __restrict__ w0  = W0 + f * H0N;
            const float* __restrict__ bb0 = b0 + f * H0N;
            const float* __restrict__ w1  = W1 + f * H0N * H1N;
            const float* __restrict__ bb1 = b1 + f * H1N;
            const float* __restrict__ w2  = W2 + f * H1N;

            float h1[H1N];
            #pragma unroll
            for (int o = 0; o < H1N; ++o) h1[o] = bb1[o];

            #pragma unroll
            for (int k = 0; k < H0N; ++k) {                 // h0 fused: never materialized
                const float h0k = fmaxf(fmaf(x, w0[k], bb0[k]), 0.0f);
                #pragma unroll
                for (int o = 0; o < H1N; ++o)
                    h1[o] = fmaf(h0k, w1[k * H1N + o], h1[o]);
            }

            float acc = b2[f];
            #pragma unroll
            for (int o = 0; o < H1N; ++o)
                acc = fmaf(fmaxf(h1[o], 0.0f), w2[o], acc);

            tile[lane * TPAD + wv * 4 + ff] = acc;
        }
    } else {
        // ---- categorical: features 48..63 ----
        const int jbase = wv * 4;            // cat index base 0..15
        #pragma unroll 1
        for (int ff = 0; ff < 4; ++ff) {
            const int j = jbase + ff;
            const float x = rowp[NNUM + j];
            const int idx = (int)x;
            tile[lane * TPAD + j] = cb[j * NCLS + idx];
        }
    }

    __syncthreads();

    // ---- coalesced store: 64 rows x 16 cols, one float4 per thread ----
    const int r  = threadIdx.x >> 2;
    const int c4 = threadIdx.x & 3;
    const float* src = &tile[r * TPAD + c4 * 4];
    float4 v = make_float4(src[0], src[1], src[2], src[3]);
    float* gout = out + ((long long)blockIdx.x * RG + r) * NCOLS + fg * 16 + c4 * 4;
    *reinterpret_cast<float4*>(gout) = v;
}

extern "C" void kernel_launch(void* const* d_in, const int* in_sizes, int n_in,
                              void* d_out, int out_size, void* d_ws, size_t ws_size,
                              hipStream_t stream) {
    const float* inp   = (const float*)d_in[0];
    const float* W0    = (const float*)d_in[1];
    const float* b0    = (const float*)d_in[2];
    const float* W1    = (const float*)d_in[3];
    const float* b1    = (const float*)d_in[4];
    const float* W2    = (const float*)d_in[5];
    const float* b2    = (const float*)d_in[6];
    const float* cbias = (const float*)d_in[7];
    float* out = (float*)d_out;

    const int nrows = 131072;
    dim3 grid(nrows / RG, 4);   // 2048 x 4 blocks
    dim3 block(BLOCK);
    gam_kernel<<<grid, block, 0, stream>>>(inp, W0, b0, W1, b1, W2, b2, cbias, out);
}